// Round 10
// baseline (431.083 us; speedup 1.0000x reference)
//
#include <hip/hip_runtime.h>

// TensorTrain: BS=16384, N_CH=8, H=256, RANK=16, N_AGGR=4, T=64, R=(16+1)*16=272
// Only r < 256 of ris is used (U_rank rows 0..15, b_rank = row 15 of tile 15).
//
// Round-11: break barrier lockstep with TWO independent blocks per CU.
// Evidence: r2(16 waves, drain)=213us, r4(16 waves, counted vmcnt)=206us,
// r10(8 waves, no spill)=231us -- all ~4000 cyc/tile vs ~2000 LDS-pipe model.
// Occupancy didn't help because all waves in a block are barrier-aligned:
// they burst on the LDS pipe together, then wait together. This round:
//   - 256-thr / 4-wave blocks, 32 samples x 1 aggregator-PAIR each; grid 1024.
//     LDS 68 KB -> 2 blocks/CU resident, independent barrier domains that
//     interleave phases (the desync occupancy-within-a-block can't give).
//   - B half-tiles (16 KB) triple-buffered, counted vmcnt(4) gate per tile
//     (never drains mid-loop; 2-tile DMA latency budget).
//   - carry back in wave-local registers + __shfl (r2-proven): the wave that
//     publishes the carry is the wave that consumes it -- the LDS carry
//     table + its barriers were pure overhead. "+1 at r=15" added at the
//     shfl read (r2 semantics), NOT baked into carry.
//   - register discipline of r10 kept: Af[8]=32 regs, 1 aggr chain/wave,
//     unroll-1 loops. Live ~80 << 128 -> no spill.
// Cost: nh read twice (once per ap) -> +128 MB FETCH, absorbed by L3/HBM.

#define N_CH   8
#define H_DIM  256
#define R_FULL 272
#define G_ALL  128             // total K-tiles = N_CH*16

typedef __bf16 bf16x8 __attribute__((ext_vector_type(8)));
typedef float  f32x4  __attribute__((ext_vector_type(4)));

union BF8 {
  bf16x8 v;
  unsigned short s[8];
  uint4 q;
};

typedef __attribute__((address_space(3))) unsigned int       lds_u32;
typedef __attribute__((address_space(1))) const unsigned int glb_u32;

static __device__ __forceinline__ unsigned short f2bf(float x) {
  union { float f; unsigned int u; } t; t.f = x;
  unsigned int u = t.u;
  return (unsigned short)((u + 0x7FFFu + ((u >> 16) & 1u)) >> 16); // RNE
}
static __device__ __forceinline__ unsigned int pk2(float a, float b) {
  return (unsigned int)f2bf(a) | ((unsigned int)f2bf(b) << 16);
}
static __device__ __forceinline__ void ll16(const void* g, void* l) {
  __builtin_amdgcn_global_load_lds((glb_u32*)g, (lds_u32*)l, 16, 0, 0);
}

// ---- prep: U[c][a][h][r<256] f32 -> bf16 in MFMA B-fragment order:
// Ubf[ca][t][ks][lane][j]  (j=0..7 bf16, 16B per lane-frag), where
//   r = t*16 + (lane&15), h = ks*32 + (lane>>4)*8 + j.
__global__ void prep_U_kernel(const float* __restrict__ U, unsigned int* __restrict__ Ubf) {
  unsigned int idx  = blockIdx.x * 256u + threadIdx.x;   // 1,048,576 total
  unsigned int jp   = idx & 3u;
  unsigned int lane = (idx >> 2) & 63u;
  unsigned int ks   = (idx >> 8) & 7u;
  unsigned int t    = (idx >> 11) & 15u;
  unsigned int ca   = idx >> 15;
  unsigned int h = ks * 32u + (lane >> 4) * 8u + jp * 2u;
  unsigned int r = t * 16u + (lane & 15u);
  const float* src = U + ((size_t)ca * 256u + h) * R_FULL + r;
  Ubf[idx] = pk2(src[0], src[R_FULL]);   // h, h+1
}

// LDS layout (static, 68 KB -> 2 blocks/CU):
//   B bufs:  3 x 16 KB ([ai][ks][lane]16B, this block's aggr pair) at 0
//   A buf:   16 KB ([sg][ks][lane]16B, 32 samples)                 at 48K
//   bias:    2 x 2 KB ([ai][r<256] f32)                            at 64K
#define SM_B(k)    ((k) * 16384)
#define SM_A       49152
#define SM_BIAS(q) (65536 + (q) * 2048)
#define SM_TOTAL   69632

__global__ __launch_bounds__(256, 2)
void tt_main(const float* __restrict__ nh,            // (BS, 8, 256)
             const float* __restrict__ ty,            // (BS, 64)
             const char*  __restrict__ Ubf,           // frag-ordered bf16 U (4 MB)
             const float* __restrict__ bB,            // (8, 4, 1, 272)
             const float* __restrict__ Ut,            // (4, 64, 16)
             const float* __restrict__ bt,            // (4, 1, 16)
             const float* __restrict__ Uo,            // (4, 16, 256)
             const float* __restrict__ bo,            // (4, 1, 256)
             float* __restrict__ out)                 // (BS, 1024)
{
  __shared__ __align__(16) char smem[SM_TOTAL];
  const int tid  = threadIdx.x;
  const int lane = tid & 63;
  const int w    = tid >> 6;           // 0..3
  const int ai   = w & 1;              // aggr within pair
  const int sg   = w >> 1;             // sample group 0..1 (16 samples)
  const int ap   = blockIdx.x & 1;     // aggregator pair
  const int sb   = blockIdx.x >> 1;    // sample block 0..511
  const int a    = ap * 2 + ai;
  const int b0   = sb * 32;            // block sample base
  const int rowb = b0 + sg * 16;       // wave sample base
  const int lr   = lane & 15;
  const int lg   = lane >> 4;

  // B half-tile loader: tile g -> buf; wave w copies 4 chunks (1 KB each).
  // Block needs aggrs {2ap, 2ap+1}: 16 chunks (ai',ks) per tile.
  auto issueB = [&](int g, int buf) {
    const int cB = g >> 4, tB = g & 15;
#pragma unroll
    for (int q = 0; q < 4; ++q) {
      const int ch = w * 4 + q;                       // 0..15
      const int ag = ap * 2 + (ch >> 3);
      const int ks = ch & 7;
      const char* gp = Ubf + ((((size_t)(cB * 4 + ag) * 16 + tB) * 8 + ks) << 10)
                           + lane * 16;
      ll16(gp, smem + SM_B(buf) + ch * 1024);
    }
  };

  // ---- carry init (before any DMA, so its loads don't tangle vmcnt):
  // rank_ris0 = ty @ U_type[a] + b_type[a]; NO +1 baked (added at shfl read).
  f32x4 carry;
  {
    float btv = bt[a * 16 + lr];
    f32x4 acc = { btv, btv, btv, btv };
#pragma unroll
    for (int ks = 0; ks < 2; ++ks) {
      BF8 utf, af;
#pragma unroll
      for (int j = 0; j < 8; ++j) {
        utf.s[j] = f2bf(Ut[a * 1024 + (ks * 32 + lg * 8 + j) * 16 + lr]);
        af.s[j]  = f2bf(ty[(size_t)(rowb + lr) * 64 + ks * 32 + lg * 8 + j]);
      }
      acc = __builtin_amdgcn_mfma_f32_16x16x32_bf16(af.v, utf.v, acc, 0, 0, 0);
    }
    carry = acc;
  }

  // ---- prologue: B(0), B(1) in flight; stage A(0) + bias(0).
  issueB(0, 0);
  issueB(1, 1);

#pragma unroll
  for (int it = 0; it < 4; ++it) {       // A(0): 1024 uint4 positions / 256 thr
    const int pos = it * 256 + tid;
    const int sgs = pos >> 9, ks = (pos >> 6) & 7, ln = pos & 63;
    const int row = sgs * 16 + (ln & 15);
    const int k0  = ks * 32 + (ln >> 4) * 8;
    const float* s = nh + ((size_t)(b0 + row) * N_CH + 0) * H_DIM + k0;
    float4 x0 = *(const float4*)s, x1 = *(const float4*)(s + 4);
    uint4 qv;
    qv.x = pk2(x0.x, x0.y); qv.y = pk2(x0.z, x0.w);
    qv.z = pk2(x1.x, x1.y); qv.w = pk2(x1.z, x1.w);
    *(uint4*)(smem + SM_A + ((sgs * 8 + ks) * 64 + ln) * 16) = qv;
  }
  {                                      // bias(0) for this block's pair
    const int idx2 = tid * 2, a_s = idx2 >> 8, r_s = idx2 & 255;
    const float* bp = bB + ((size_t)0 * 4 + ap * 2 + a_s) * R_FULL + r_s;
    float2 bv = { bp[0], bp[1] };
    *(float2*)(smem + SM_BIAS(0) + idx2 * 4) = bv;
  }
  asm volatile("s_waitcnt lgkmcnt(0)" ::: "memory");
  __builtin_amdgcn_s_barrier();

  BF8   Af[8];
  f32x4 part;
  int   rb = 0;                          // read-buffer = g % 3

  // ---- channel scan: per tile, gate on vmcnt(4) (my tile-g DMA done,
  // tile-g+1's 4 may fly) + barrier; issue DMA(g+2); never drain mid-loop.
#pragma unroll 1
  for (int c = 0; c < N_CH; ++c) {
    const int cb = c & 1;
#pragma unroll 1
    for (int t = 0; t < 16; ++t) {
      const int g = c * 16 + t;
      if (g == G_ALL - 1) asm volatile("s_waitcnt vmcnt(0)" ::: "memory");
      else                asm volatile("s_waitcnt vmcnt(4)" ::: "memory");
      __builtin_amdgcn_s_barrier();

      const int ib = (rb >= 1) ? rb - 1 : 2;       // (rb+2)%3
      if (c < 7 && (t == 4 || t == 10)) {
        // A(c+1) half-stage: f32 loads BEFORE issueB so the pack's wait
        // leaves the fresh DMA(g+2) in flight.
        float4 x[2][2];
#pragma unroll
        for (int p = 0; p < 2; ++p) {
          const int pos = (t == 10 ? 512 : 0) + p * 256 + tid;
          const int sgs = pos >> 9, ks = (pos >> 6) & 7, ln = pos & 63;
          const int row = sgs * 16 + (ln & 15);
          const int k0  = ks * 32 + (ln >> 4) * 8;
          const float* s = nh + ((size_t)(b0 + row) * N_CH + (c + 1)) * H_DIM + k0;
          x[p][0] = *(const float4*)s;
          x[p][1] = *(const float4*)(s + 4);
        }
        issueB(g + 2, ib);
        asm volatile("s_waitcnt vmcnt(4)" ::: "memory");
#pragma unroll
        for (int p = 0; p < 2; ++p) {
          const int pos = (t == 10 ? 512 : 0) + p * 256 + tid;
          const int sgs = pos >> 9, ks = (pos >> 6) & 7, ln = pos & 63;
          uint4 qv;
          qv.x = pk2(x[p][0].x, x[p][0].y); qv.y = pk2(x[p][0].z, x[p][0].w);
          qv.z = pk2(x[p][1].x, x[p][1].y); qv.w = pk2(x[p][1].z, x[p][1].w);
          *(uint4*)(smem + SM_A + ((sgs * 8 + ks) * 64 + ln) * 16) = qv;
        }
        asm volatile("s_waitcnt lgkmcnt(0)" ::: "memory");
      } else if (c < 7 && t == 7) {
        // bias(c+1) into the idle buffer
        const int idx2 = tid * 2, a_s = idx2 >> 8, r_s = idx2 & 255;
        const float* bp = bB + ((size_t)(c + 1) * 4 + ap * 2 + a_s) * R_FULL + r_s;
        float2 bv = { bp[0], bp[1] };
        issueB(g + 2, ib);
        asm volatile("s_waitcnt vmcnt(4)" ::: "memory");
        *(float2*)(smem + SM_BIAS(cb ^ 1) + idx2 * 4) = bv;
        asm volatile("s_waitcnt lgkmcnt(0)" ::: "memory");
      } else if (g + 2 < G_ALL) {
        issueB(g + 2, ib);
      }

      if (t == 0) {
        // A fragments for this wave's sample-group (reused for 16 tiles)
#pragma unroll
        for (int ks = 0; ks < 8; ++ks)
          Af[ks].q = *(const uint4*)(smem + SM_A + ((sg * 8 + ks) * 64 + lane) * 16);
        part[0] = part[1] = part[2] = part[3] = 0.f;
      }

      // ---- compute tile t: acc = A(16x256) x B(256x16); bias folded after.
      const char* Bb = smem + SM_B(rb) + (ai * 8) * 1024 + lane * 16;
      f32x4 acc = { 0.f, 0.f, 0.f, 0.f };
      __builtin_amdgcn_s_setprio(1);
#pragma unroll
      for (int ks = 0; ks < 8; ++ks) {
        BF8 bf;
        bf.q = *(const uint4*)(Bb + ks * 1024);
        acc = __builtin_amdgcn_mfma_f32_16x16x32_bf16(Af[ks].v, bf.v, acc, 0, 0, 0);
      }
      __builtin_amdgcn_s_setprio(0);

      // fused scan step: part += (carry[r=t] + (t==15)) * (acc + bias)
      const float bias  = *(const float*)(smem + SM_BIAS(cb) + (ai * 256 + t * 16 + lr) * 4);
      const float extra = (t == 15) ? 1.0f : 0.0f;
      const int   srcl  = (lane & 48) | t;
#pragma unroll
      for (int i = 0; i < 4; ++i) {
        float cv = __shfl(carry[i], srcl, 64) + extra;
        part[i] += cv * (acc[i] + bias);
      }
      rb = (rb + 1 >= 3) ? 0 : rb + 1;
    }
    carry = part;                        // wave-local: producer == consumer
  }

  // ---- epilogue: out[b][a*256+h] = carry[b][a][:] @ Uo[a][:][h] + bo[a][h]
  float uo[4][16], bov[4];
#pragma unroll
  for (int chk = 0; chk < 4; ++chk) {
    bov[chk] = bo[a * 256 + chk * 64 + lane];
#pragma unroll
    for (int r = 0; r < 16; ++r)
      uo[chk][r] = Uo[(size_t)a * 4096 + r * 256 + chk * 64 + lane];
  }
#pragma unroll
  for (int gq = 0; gq < 4; ++gq)
#pragma unroll
    for (int i = 0; i < 4; ++i) {
      const int m = gq * 4 + i;
      float cvv[16];
#pragma unroll
      for (int r = 0; r < 16; ++r) cvv[r] = __shfl(carry[i], (gq << 4) | r, 64);
#pragma unroll
      for (int chk = 0; chk < 4; ++chk) {
        float v = bov[chk];
#pragma unroll
        for (int r = 0; r < 16; ++r) v += cvv[r] * uo[chk][r];
        out[(size_t)(rowb + m) * 1024 + a * 256 + chk * 64 + lane] = v;
      }
    }
}

extern "C" void kernel_launch(void* const* d_in, const int* in_sizes, int n_in,
                              void* d_out, int out_size, void* d_ws, size_t ws_size,
                              hipStream_t stream) {
  const float* nh = (const float*)d_in[0];   // neighbour_h (16384, 8, 256)
  const float* ty = (const float*)d_in[1];   // type_embs   (16384, 64)
  const float* U  = (const float*)d_in[2];   // U           (8, 4, 256, 272)
  const float* bB = (const float*)d_in[3];   // b           (8, 4, 1, 272)
  const float* Ut = (const float*)d_in[4];   // U_type      (4, 64, 16)
  const float* bt = (const float*)d_in[5];   // b_type      (4, 1, 16)
  const float* Uo = (const float*)d_in[6];   // U_output    (4, 16, 256)
  const float* bo = (const float*)d_in[7];   // b_output    (4, 1, 256)
  float* out = (float*)d_out;

  unsigned int* Ubf32 = (unsigned int*)d_ws; // 4 MB frag-ordered bf16 U

  prep_U_kernel<<<4096, 256, 0, stream>>>(U, Ubf32);

  tt_main<<<1024, 256, 0, stream>>>(nh, ty, (const char*)d_ws,
                                    bB, Ut, bt, Uo, bo, out);
}